// Round 8
// baseline (851.737 us; speedup 1.0000x reference)
//
#include <hip/hip_runtime.h>

// Problem constants
#define K_   4096
#define S0   67108864     // N*M*H*W*K
#define NP   16384        // N*M*H*W
#define NEG_INF_ (-1.0e9f)

typedef float fx4 __attribute__((ext_vector_type(4)));  // NT-store-compatible

// --- tiny pre-kernel: code_usage -> expo, stored in ws[0] ---
__global__ __launch_bounds__(256) void usage_kernel(const float* __restrict__ freq,
                                                    float* __restrict__ ws) {
  __shared__ int sc[256];
  int c = 0;
  for (int i = threadIdx.x; i < 4 * K_; i += 256) c += (freq[i] > 1e-7f) ? 1 : 0;
  sc[threadIdx.x] = c;
  __syncthreads();
  for (int s = 128; s > 0; s >>= 1) {
    if (threadIdx.x < s) sc[threadIdx.x] += sc[threadIdx.x + s];
    __syncthreads();
  }
  if (threadIdx.x == 0) {
    float u = (float)sc[0] * (1.0f / 16384.0f);   // exact: count / 2^14
    u = fminf(fmaxf(u, 0.0f), 1.0f);
    ws[0] = 12.0f - 11.0f * (u * u);              // expo = BITS - (BITS-1)*u^2
  }
}

__device__ __forceinline__ void amax_comb(float& v, int& i, float v2, int i2) {
  // max with first-index (min idx) tie-break — associative & commutative
  if (v2 > v || (v2 == v && i2 < i)) { v = v2; i = i2; }
}

// TP=2 + chunked codebook + reg double-buffered dn/gn prefetch.
// Natural VGPR demand ~60-80 under the (256,2) cap of 128 -> spill-free,
// occupancy limited by 512/VGPR (~6-8 waves/SIMD). Cross-iteration MLP:
// kt+1 loads are in flight during kt's ~200-cycle compute phase.
__global__ __launch_bounds__(256, 2) void mcq_kernel(
    const float* __restrict__ x,    // (N, M*D, H, W)
    const float* __restrict__ cb,   // (M, K, D)
    const float* __restrict__ freq, // (M, K)
    const float* __restrict__ temp, // (M)
    const float* __restrict__ dn,   // (N, M, H, W, K)
    const float* __restrict__ gn,   // (N, M, H, W, K)
    const float* __restrict__ ws,
    float* __restrict__ out)
{
  const int tid   = threadIdx.x;
  const int nm    = blockIdx.x >> 9;   // 0..15  (n*M+m)
  const int ptile = blockIdx.x & 511;  // 0..511
  const int m     = nm & 3;
  const int hw0   = ptile << 1;        // 2 positions
  const int rowbase = (nm << 10) + hw0;

  __shared__ float xs[2][32];
  __shared__ float x2s[2];
  if (tid < 64) {
    const int d = tid >> 1, p = tid & 1;
    xs[p][d] = x[((size_t)(nm >> 2) * 128 + (size_t)m * 32 + d) * 1024 + hw0 + p];
  }
  __syncthreads();
  if (tid < 2) {
    float s = 0.f;
    #pragma unroll
    for (int d = 0; d < 32; ++d) s += xs[tid][d] * xs[tid][d];
    x2s[tid] = s;
  }
  __syncthreads();

  const float expo = ws[0];
  const float tlb  = fmaxf(temp[m], 1e-7f);  // lower_bound fwd
  const float* __restrict__ cbm   = cb + (size_t)m * K_ * 32;
  const float* __restrict__ freqm = freq + m * K_;
  float* __restrict__ out_sample = out;
  float* __restrict__ out_code   = out + S0;
  float* __restrict__ out_onehot = out + S0 + NP;
  float* __restrict__ out_logit  = out + (size_t)2 * S0 + NP;

  float x2r[2];
  #pragma unroll
  for (int p = 0; p < 2; ++p) x2r[p] = x2s[p];

  float lval[2], gval[2];
  int   lidx[2], gidx[2];
  #pragma unroll
  for (int p = 0; p < 2; ++p) {
    lval[p] = -3.402823466e38f; gval[p] = -3.402823466e38f;
    lidx[p] = 0; gidx[p] = 0;
  }

  const size_t base0 = (size_t)rowbase * K_;

  // prologue: prefetch kt=0 tile
  float dnv[2], gnv[2];
  #pragma unroll
  for (int p = 0; p < 2; ++p) {
    const size_t off = base0 + (size_t)p * K_ + tid;
    dnv[p] = __builtin_nontemporal_load(dn + off);
    gnv[p] = __builtin_nontemporal_load(gn + off);
  }
  float fv = freqm[tid];

  for (int kt = 0; kt < 16; ++kt) {
    const int k = (kt << 8) + tid;
    // 1) prefetch NEXT tile's streaming loads (in flight during compute)
    float dnv_n[2], gnv_n[2], fv_n = 0.f;
    if (kt < 15) {
      const int kn = k + 256;
      #pragma unroll
      for (int p = 0; p < 2; ++p) {
        const size_t off = base0 + (size_t)p * K_ + kn;
        dnv_n[p] = __builtin_nontemporal_load(dn + off);
        gnv_n[p] = __builtin_nontemporal_load(gn + off);
      }
      fv_n = freqm[kn];
    }
    // 2) codebook row, chunked (one float4 live at a time; L2-resident)
    float dotv[2];
    dotv[0] = 0.f; dotv[1] = 0.f;
    float c2 = 0.f;
    const float4* __restrict__ cp = (const float4*)(cbm + (size_t)k * 32);
    #pragma unroll
    for (int j = 0; j < 8; ++j) {
      const float4 c = cp[j];
      c2 += c.x * c.x; c2 += c.y * c.y; c2 += c.z * c.z; c2 += c.w * c.w;
      #pragma unroll
      for (int p = 0; p < 2; ++p) {
        const float4 xq = *(const float4*)&xs[p][4 * j];
        float a = dotv[p];
        a = fmaf(c.x, xq.x, a);
        a = fmaf(c.y, xq.y, a);
        a = fmaf(c.z, xq.z, a);
        a = fmaf(c.w, xq.w, a);
        dotv[p] = a;
      }
    }
    // 3) logit + mask + argmax updates (numerics identical to proven rounds)
    #pragma unroll
    for (int p = 0; p < 2; ++p) {
      const size_t off = base0 + (size_t)p * K_ + k;
      const float dist = (x2r[p] + c2) - 2.0f * dotv[p];
      float lg = dist * (-0.015625f) * tlb;   // (-dist/64)*tlb
      const float pv = exp2f(expo * log2f(dnv[p]));
      if (pv < fv) lg = lg + NEG_INF_;
      __builtin_nontemporal_store(lg, out_logit + off);
      if (lg > lval[p]) { lval[p] = lg; lidx[p] = k; }
      const float lgg = lg + gnv[p];
      if (lgg > gval[p]) { gval[p] = lgg; gidx[p] = k; }
    }
    // 4) rotate buffers
    dnv[0] = dnv_n[0]; dnv[1] = dnv_n[1];
    gnv[0] = gnv_n[0]; gnv[1] = gnv_n[1];
    fv = fv_n;
  }

  // cross-thread argmax reduction: per-wave butterfly, then 4 partials via LDS
  __shared__ float rv[4][4];
  __shared__ int   ri[4][4];
  __shared__ int   widx[2][2];   // [0]=logit winner (one_hot), [1]=gumbel winner (sample)
  const int wave = tid >> 6, lane = tid & 63;
  #pragma unroll
  for (int p = 0; p < 2; ++p) {
    float v = lval[p]; int i = lidx[p];
    #pragma unroll
    for (int s = 1; s < 64; s <<= 1) {
      float v2 = __shfl_xor(v, s, 64);
      int   i2 = __shfl_xor(i, s, 64);
      amax_comb(v, i, v2, i2);
    }
    if (lane == 0) { rv[wave][p*2] = v; ri[wave][p*2] = i; }
    v = gval[p]; i = gidx[p];
    #pragma unroll
    for (int s = 1; s < 64; s <<= 1) {
      float v2 = __shfl_xor(v, s, 64);
      int   i2 = __shfl_xor(i, s, 64);
      amax_comb(v, i, v2, i2);
    }
    if (lane == 0) { rv[wave][p*2+1] = v; ri[wave][p*2+1] = i; }
  }
  __syncthreads();
  if (tid < 4) {
    float v = rv[0][tid]; int i = ri[0][tid];
    amax_comb(v, i, rv[1][tid], ri[1][tid]);
    amax_comb(v, i, rv[2][tid], ri[2][tid]);
    amax_comb(v, i, rv[3][tid], ri[3][tid]);
    const int p   = tid >> 1;
    const int sel = tid & 1;
    widx[sel][p] = i;
    if (sel == 0) out_code[rowbase + p] = (float)i;   // argmax(logit) -> code
  }
  __syncthreads();

  // tail: write full one-hot rows for sample and one_hot (coalesced NT fx4)
  #pragma unroll
  for (int p = 0; p < 2; ++p) {
    const size_t rowoff = base0 + (size_t)p * K_;
    const int wl = widx[0][p];   // one_hot winner  (argmax logit)
    const int wg = widx[1][p];   // sample winner   (argmax logit+gumbel)
    #pragma unroll
    for (int j = 0; j < 4; ++j) {
      const int k0 = (j << 10) + (tid << 2);
      fx4 vo, vs;
      vo.x = (k0 + 0 == wl) ? 1.0f : 0.0f;
      vo.y = (k0 + 1 == wl) ? 1.0f : 0.0f;
      vo.z = (k0 + 2 == wl) ? 1.0f : 0.0f;
      vo.w = (k0 + 3 == wl) ? 1.0f : 0.0f;
      vs.x = (k0 + 0 == wg) ? 1.0f : 0.0f;
      vs.y = (k0 + 1 == wg) ? 1.0f : 0.0f;
      vs.z = (k0 + 2 == wg) ? 1.0f : 0.0f;
      vs.w = (k0 + 3 == wg) ? 1.0f : 0.0f;
      __builtin_nontemporal_store(vo, (fx4*)(out_onehot + rowoff + k0));
      __builtin_nontemporal_store(vs, (fx4*)(out_sample + rowoff + k0));
    }
  }
}

extern "C" void kernel_launch(void* const* d_in, const int* in_sizes, int n_in,
                              void* d_out, int out_size, void* d_ws, size_t ws_size,
                              hipStream_t stream) {
  const float* x    = (const float*)d_in[0];
  const float* cb   = (const float*)d_in[1];
  const float* freq = (const float*)d_in[2];
  const float* temp = (const float*)d_in[3];
  const float* dn   = (const float*)d_in[4];
  const float* gn   = (const float*)d_in[5];
  float* out = (float*)d_out;
  float* ws  = (float*)d_ws;

  // no memset needed: kernel writes every element of all four outputs
  usage_kernel<<<1, 256, 0, stream>>>(freq, ws);
  mcq_kernel<<<8192, 256, 0, stream>>>(x, cb, freq, temp, dn, gn, ws, out);
}

// Round 9
// 326.607 us; speedup vs baseline: 2.6078x; 2.6078x over previous
//
#include <hip/hip_runtime.h>

// Problem constants
#define K_   4096
#define S0   67108864     // N*M*H*W*K
#define NP   16384        // N*M*H*W
#define NEG_INF_ (-1.0e9f)
#define LCB_STRIDE 36     // floats; 144 B rows: 16-B aligned, uniform bank spread

typedef float fx4 __attribute__((ext_vector_type(4)));  // NT-store-compatible

// --- tiny pre-kernel: code_usage -> expo, stored in ws[0] ---
__global__ __launch_bounds__(256) void usage_kernel(const float* __restrict__ freq,
                                                    float* __restrict__ ws) {
  __shared__ int sc[256];
  int c = 0;
  for (int i = threadIdx.x; i < 4 * K_; i += 256) c += (freq[i] > 1e-7f) ? 1 : 0;
  sc[threadIdx.x] = c;
  __syncthreads();
  for (int s = 128; s > 0; s >>= 1) {
    if (threadIdx.x < s) sc[threadIdx.x] += sc[threadIdx.x + s];
    __syncthreads();
  }
  if (threadIdx.x == 0) {
    float u = (float)sc[0] * (1.0f / 16384.0f);   // exact: count / 2^14
    u = fminf(fmaxf(u, 0.0f), 1.0f);
    ws[0] = 12.0f - 11.0f * (u * u);              // expo = BITS - (BITS-1)*u^2
  }
}

__device__ __forceinline__ void amax_comb(float& v, int& i, float v2, int i2) {
  // max with first-index (min idx) tie-break — associative & commutative
  if (v2 > v || (v2 == v && i2 < i)) { v = v2; i = i2; }
}

// R7 structure (TP=4, 4096 blocks, fused tail) + LDS-staged codebook tile:
// per kt the 256-row (32 KB) tile is CONTIGUOUS in cb -> cooperative load is
// perfectly coalesced, fixing R8's diagnosed uncoalesced-codebook bottleneck
// (64 lanes x distinct 128-B lines per cp[j] access). ds rows padded to 36
// floats for alignment + uniform bank distribution. FMA order unchanged.
__global__ __launch_bounds__(256, 2) void mcq_kernel(
    const float* __restrict__ x,    // (N, M*D, H, W)
    const float* __restrict__ cb,   // (M, K, D)
    const float* __restrict__ freq, // (M, K)
    const float* __restrict__ temp, // (M)
    const float* __restrict__ dn,   // (N, M, H, W, K)
    const float* __restrict__ gn,   // (N, M, H, W, K)
    const float* __restrict__ ws,
    float* __restrict__ out)
{
  const int tid   = threadIdx.x;
  const int nm    = blockIdx.x >> 8;   // 0..15  (n*M+m)
  const int ptile = blockIdx.x & 255;  // 0..255
  const int m     = nm & 3;
  const int hw0   = ptile << 2;        // 4 positions
  const int rowbase = (nm << 10) + hw0;

  __shared__ float xs[4][32];
  __shared__ float x2s[4];
  __shared__ float lcb[256 * LCB_STRIDE];   // 36 KB staged codebook tile
  if (tid < 128) {
    const int d = tid >> 2, p = tid & 3;
    xs[p][d] = x[((size_t)(nm >> 2) * 128 + (size_t)m * 32 + d) * 1024 + hw0 + p];
  }
  __syncthreads();
  if (tid < 4) {
    float s = 0.f;
    #pragma unroll
    for (int d = 0; d < 32; ++d) s += xs[tid][d] * xs[tid][d];
    x2s[tid] = s;
  }
  __syncthreads();

  const float expo = ws[0];
  const float tlb  = fmaxf(temp[m], 1e-7f);  // lower_bound fwd
  const float* __restrict__ cbm   = cb + (size_t)m * K_ * 32;
  const float4* __restrict__ cb4  = (const float4*)cbm;
  const float* __restrict__ freqm = freq + m * K_;
  float* __restrict__ out_sample = out;
  float* __restrict__ out_code   = out + S0;
  float* __restrict__ out_onehot = out + S0 + NP;
  float* __restrict__ out_logit  = out + (size_t)2 * S0 + NP;

  float x2r[4];
  #pragma unroll
  for (int p = 0; p < 4; ++p) x2r[p] = x2s[p];

  float lval[4], gval[4];
  int   lidx[4], gidx[4];
  #pragma unroll
  for (int p = 0; p < 4; ++p) {
    lval[p] = -3.402823466e38f; gval[p] = -3.402823466e38f;
    lidx[p] = 0; gidx[p] = 0;
  }

  const size_t base0 = (size_t)rowbase * K_;

  for (int kt = 0; kt < 16; ++kt) {
    const int k = (kt << 8) + tid;
    // 1) batch-issue streaming loads (latency overlaps the LDS fill below)
    float dnv[4], gnv[4];
    #pragma unroll
    for (int p = 0; p < 4; ++p) {
      const size_t off = base0 + (size_t)p * K_ + k;
      dnv[p] = __builtin_nontemporal_load(dn + off);
      gnv[p] = __builtin_nontemporal_load(gn + off);
    }
    const float fv = freqm[k];
    // 2) cooperative COALESCED tile load: tile is contiguous (cb4[kt*2048+f])
    #pragma unroll
    for (int it = 0; it < 8; ++it) {
      const int f = (it << 8) + tid;            // 0..2047
      const float4 v = cb4[(kt << 11) + f];
      const int r = f >> 3, j = f & 7;
      *(float4*)&lcb[r * LCB_STRIDE + (j << 2)] = v;
    }
    __syncthreads();
    // 3) per-thread row dot from LDS — SAME values, SAME FMA order as proven
    float dotv[4];
    #pragma unroll
    for (int p = 0; p < 4; ++p) dotv[p] = 0.f;
    float c2 = 0.f;
    #pragma unroll
    for (int j = 0; j < 8; ++j) {
      const float4 c = *(const float4*)&lcb[tid * LCB_STRIDE + (j << 2)];
      c2 += c.x * c.x; c2 += c.y * c.y; c2 += c.z * c.z; c2 += c.w * c.w;
      #pragma unroll
      for (int p = 0; p < 4; ++p) {
        const float4 xq = *(const float4*)&xs[p][4 * j];
        float a = dotv[p];
        a = fmaf(c.x, xq.x, a);
        a = fmaf(c.y, xq.y, a);
        a = fmaf(c.z, xq.z, a);
        a = fmaf(c.w, xq.w, a);
        dotv[p] = a;
      }
    }
    // 4) logit + mask + argmax updates (numerics identical to proven rounds)
    #pragma unroll
    for (int p = 0; p < 4; ++p) {
      const size_t off = base0 + (size_t)p * K_ + k;
      const float dist = (x2r[p] + c2) - 2.0f * dotv[p];
      float lg = dist * (-0.015625f) * tlb;   // (-dist/64)*tlb
      const float pv = exp2f(expo * log2f(dnv[p]));
      if (pv < fv) lg = lg + NEG_INF_;
      __builtin_nontemporal_store(lg, out_logit + off);
      if (lg > lval[p]) { lval[p] = lg; lidx[p] = k; }
      const float lgg = lg + gnv[p];
      if (lgg > gval[p]) { gval[p] = lgg; gidx[p] = k; }
    }
    __syncthreads();   // lcb reused next kt
  }

  // cross-thread argmax reduction: per-wave butterfly, then 4 partials via LDS
  __shared__ float rv[4][8];
  __shared__ int   ri[4][8];
  __shared__ int   widx[2][4];   // [0]=logit winner (one_hot), [1]=gumbel winner (sample)
  const int wave = tid >> 6, lane = tid & 63;
  #pragma unroll
  for (int p = 0; p < 4; ++p) {
    float v = lval[p]; int i = lidx[p];
    #pragma unroll
    for (int s = 1; s < 64; s <<= 1) {
      float v2 = __shfl_xor(v, s, 64);
      int   i2 = __shfl_xor(i, s, 64);
      amax_comb(v, i, v2, i2);
    }
    if (lane == 0) { rv[wave][p*2] = v; ri[wave][p*2] = i; }
    v = gval[p]; i = gidx[p];
    #pragma unroll
    for (int s = 1; s < 64; s <<= 1) {
      float v2 = __shfl_xor(v, s, 64);
      int   i2 = __shfl_xor(i, s, 64);
      amax_comb(v, i, v2, i2);
    }
    if (lane == 0) { rv[wave][p*2+1] = v; ri[wave][p*2+1] = i; }
  }
  __syncthreads();
  if (tid < 8) {
    float v = rv[0][tid]; int i = ri[0][tid];
    amax_comb(v, i, rv[1][tid], ri[1][tid]);
    amax_comb(v, i, rv[2][tid], ri[2][tid]);
    amax_comb(v, i, rv[3][tid], ri[3][tid]);
    const int p   = tid >> 1;
    const int sel = tid & 1;
    widx[sel][p] = i;
    if (sel == 0) out_code[rowbase + p] = (float)i;   // argmax(logit) -> code
  }
  __syncthreads();

  // tail: write full one-hot rows for sample and one_hot (coalesced NT fx4)
  #pragma unroll
  for (int p = 0; p < 4; ++p) {
    const size_t rowoff = base0 + (size_t)p * K_;
    const int wl = widx[0][p];   // one_hot winner  (argmax logit)
    const int wg = widx[1][p];   // sample winner   (argmax logit+gumbel)
    #pragma unroll
    for (int j = 0; j < 4; ++j) {
      const int k0 = (j << 10) + (tid << 2);
      fx4 vo, vs;
      vo.x = (k0 + 0 == wl) ? 1.0f : 0.0f;
      vo.y = (k0 + 1 == wl) ? 1.0f : 0.0f;
      vo.z = (k0 + 2 == wl) ? 1.0f : 0.0f;
      vo.w = (k0 + 3 == wl) ? 1.0f : 0.0f;
      vs.x = (k0 + 0 == wg) ? 1.0f : 0.0f;
      vs.y = (k0 + 1 == wg) ? 1.0f : 0.0f;
      vs.z = (k0 + 2 == wg) ? 1.0f : 0.0f;
      vs.w = (k0 + 3 == wg) ? 1.0f : 0.0f;
      __builtin_nontemporal_store(vo, (fx4*)(out_onehot + rowoff + k0));
      __builtin_nontemporal_store(vs, (fx4*)(out_sample + rowoff + k0));
    }
  }
}

extern "C" void kernel_launch(void* const* d_in, const int* in_sizes, int n_in,
                              void* d_out, int out_size, void* d_ws, size_t ws_size,
                              hipStream_t stream) {
  const float* x    = (const float*)d_in[0];
  const float* cb   = (const float*)d_in[1];
  const float* freq = (const float*)d_in[2];
  const float* temp = (const float*)d_in[3];
  const float* dn   = (const float*)d_in[4];
  const float* gn   = (const float*)d_in[5];
  float* out = (float*)d_out;
  float* ws  = (float*)d_ws;

  // no memset needed: kernel writes every element of all four outputs
  usage_kernel<<<1, 256, 0, stream>>>(freq, ws);
  mcq_kernel<<<4096, 256, 0, stream>>>(x, cb, freq, temp, dn, gn, ws, out);
}